// Round 1
// baseline (4461.139 us; speedup 1.0000x reference)
//
#include <hip/hip_runtime.h>
#include <cstddef>
#include <cstdint>

#define NN 50000   // nodes
#define EE 640000  // edges
#define FD 128     // feature dim (F_IN == DIM == 128)

// ---------------- copy: agg = h (self term of GIN) ----------------
__global__ __launch_bounds__(256) void k_copy(const float* __restrict__ in,
                                              float* __restrict__ out) {
  int i = blockIdx.x * 256 + threadIdx.x;  // grid sized exactly: NN*FD/4 elements
  reinterpret_cast<float4*>(out)[i] = reinterpret_cast<const float4*>(in)[i];
}

// ---------------- scatter: agg[dst] += h[src] (fp32 HW atomics) ----------------
__global__ __launch_bounds__(256) void k_scatter(const float* __restrict__ h,
                                                 const int* __restrict__ src,
                                                 const int* __restrict__ dst,
                                                 float* __restrict__ agg) {
  int t = blockIdx.x * 256 + threadIdx.x;  // EE*32 threads, 1 float4 each
  int e = t >> 5;
  int q = (t & 31) << 2;
  int s = src[e];
  int d = dst[e];
  float4 v = *reinterpret_cast<const float4*>(h + (size_t)s * FD + q);
  float* p = agg + (size_t)d * FD + q;
  // unsafeAtomicAdd -> global_atomic_add_f32 (no CAS loop)
  unsafeAtomicAdd(p + 0, v.x);
  unsafeAtomicAdd(p + 1, v.y);
  unsafeAtomicAdd(p + 2, v.z);
  unsafeAtomicAdd(p + 3, v.w);
}

// ---------------- fused GEMM: O = relu(opt_bn(A @ W + b)) ----------------
// A: [M,128], W: [128,128] row-major, tile 64 rows x 128 cols per block of 256.
// LDS: A^T chunk [64k][64r] (+pad) and W chunk [64k][128c] (+pad). 4x8 regs/thread.
__global__ __launch_bounds__(256) void k_gemm(const float* __restrict__ A,
                                              const float* __restrict__ W,
                                              const float* __restrict__ bias,
                                              const float* __restrict__ gg,
                                              const float* __restrict__ bb,
                                              const float* __restrict__ rm,
                                              const float* __restrict__ rv,
                                              int use_bn,
                                              float* __restrict__ O, int M) {
  __shared__ float At[64][68];   // [k][r], pad 68 to spread store banks
  __shared__ float Ws[64][132];  // [k][c], pad 132 -> conflict-free b128 reads
  const int t  = threadIdx.x;
  const int tx = t & 15;   // col group: cols tx*8 .. tx*8+7
  const int ty = t >> 4;   // row group: rows ty*4 .. ty*4+3
  const int rowBase = blockIdx.x * 64;

  float acc[4][8] = {};

  for (int kc = 0; kc < 2; ++kc) {
    const int k0 = kc * 64;
    // stage A (transposed): 64 rows x 64 k
#pragma unroll
    for (int i = 0; i < 4; ++i) {
      int idx = t + i * 256;
      int row = idx >> 4;         // 0..63
      int kg  = (idx & 15) << 2;  // 0..60
      int r = rowBase + row;
      float4 v = make_float4(0.f, 0.f, 0.f, 0.f);
      if (r < M) v = *reinterpret_cast<const float4*>(A + (size_t)r * FD + k0 + kg);
      At[kg + 0][row] = v.x;
      At[kg + 1][row] = v.y;
      At[kg + 2][row] = v.z;
      At[kg + 3][row] = v.w;
    }
    // stage W: 64 k x 128 c
#pragma unroll
    for (int i = 0; i < 8; ++i) {
      int idx = t + i * 256;
      int wr = idx >> 5;          // 0..63
      int wc = (idx & 31) << 2;   // 0..124
      *reinterpret_cast<float4*>(&Ws[wr][wc]) =
          *reinterpret_cast<const float4*>(W + (size_t)(k0 + wr) * FD + wc);
    }
    __syncthreads();

#pragma unroll 8
    for (int k = 0; k < 64; ++k) {
      const float4 a  = *reinterpret_cast<const float4*>(&At[k][ty << 2]);
      const float4 w0 = *reinterpret_cast<const float4*>(&Ws[k][tx << 3]);
      const float4 w1 = *reinterpret_cast<const float4*>(&Ws[k][(tx << 3) + 4]);
      const float av[4] = {a.x, a.y, a.z, a.w};
      const float wv[8] = {w0.x, w0.y, w0.z, w0.w, w1.x, w1.y, w1.z, w1.w};
#pragma unroll
      for (int i = 0; i < 4; ++i)
#pragma unroll
        for (int j = 0; j < 8; ++j)
          acc[i][j] = fmaf(av[i], wv[j], acc[i][j]);
    }
    __syncthreads();
  }

  // epilogue: fold bias (+ BN eval) + relu
  const int c0 = tx << 3;
  float sc[8], sh[8];
#pragma unroll
  for (int j = 0; j < 8; ++j) {
    int c = c0 + j;
    if (use_bn) {
      float s = gg[c] * rsqrtf(rv[c] + 1e-5f);
      sc[j] = s;
      sh[j] = (bias[c] - rm[c]) * s + bb[c];
    } else {
      sc[j] = 1.f;
      sh[j] = bias[c];
    }
  }
#pragma unroll
  for (int i = 0; i < 4; ++i) {
    int r = rowBase + (ty << 2) + i;
    if (r < M) {
      float o[8];
#pragma unroll
      for (int j = 0; j < 8; ++j) {
        float v = fmaf(acc[i][j], sc[j], sh[j]);
        o[j] = v > 0.f ? v : 0.f;
      }
      *reinterpret_cast<float4*>(O + (size_t)r * FD + c0) =
          make_float4(o[0], o[1], o[2], o[3]);
      *reinterpret_cast<float4*>(O + (size_t)r * FD + c0 + 4) =
          make_float4(o[4], o[5], o[6], o[7]);
    }
  }
}

// ---------------- U/V: per-node logit halves. U = h @ clsW[0:128], V = h @ clsW[128:256]
__global__ __launch_bounds__(256) void k_uv(const float* __restrict__ h,
                                            const float* __restrict__ clsW,
                                            float* __restrict__ U,
                                            float* __restrict__ V) {
  int t = blockIdx.x * 256 + threadIdx.x;
  int r = t / 12;
  int c = t % 12;
  if (r >= NN) return;
  int cc = (c < 6) ? c : c - 6;
  int base = (c < 6) ? 0 : FD;
  const float* hr = h + (size_t)r * FD;
  float acc = 0.f;
#pragma unroll 8
  for (int k = 0; k < FD; ++k)
    acc = fmaf(hr[k], clsW[(size_t)(base + k) * 6 + cc], acc);
  if (c < 6) U[(size_t)r * 6 + cc] = acc;
  else       V[(size_t)r * 6 + cc] = acc;
}

// ---------------- edge kernel: e = [h[src], h[dst]]; logits = U[src]+V[dst]+b ----
__global__ __launch_bounds__(256) void k_edge(const float* __restrict__ h,
                                              const int* __restrict__ src,
                                              const int* __restrict__ dst,
                                              const float* __restrict__ U,
                                              const float* __restrict__ V,
                                              const float* __restrict__ clsB,
                                              float* __restrict__ outL,
                                              float* __restrict__ outE) {
  int eid  = blockIdx.x * 4 + (threadIdx.x >> 6);  // one wave per edge
  int lane = threadIdx.x & 63;
  int s = src[eid];
  int d = dst[eid];
  int node = (lane < 32) ? s : d;
  int f = (lane & 31) << 2;
  float4 v = *reinterpret_cast<const float4*>(h + (size_t)node * FD + f);
  *reinterpret_cast<float4*>(outE + (size_t)eid * 256 + (lane << 2)) = v;
  if (lane < 6)
    outL[(size_t)eid * 6 + lane] = U[(size_t)s * 6 + lane] + V[(size_t)d * 6 + lane] + clsB[lane];
}

extern "C" void kernel_launch(void* const* d_in, const int* in_sizes, int n_in,
                              void* d_out, int out_size, void* d_ws, size_t ws_size,
                              hipStream_t stream) {
  const float* x     = (const float*)d_in[0];
  const int*   ei    = (const int*)d_in[1];
  const int*   src   = ei;
  const int*   dst   = ei + EE;
  // d_in[2] = batch (unused in eval path)
  const float* c1_W1 = (const float*)d_in[3];
  const float* c1_b1 = (const float*)d_in[4];
  const float* c1_g  = (const float*)d_in[5];
  const float* c1_be = (const float*)d_in[6];
  const float* c1_rm = (const float*)d_in[7];
  const float* c1_rv = (const float*)d_in[8];
  const float* c1_W2 = (const float*)d_in[9];
  const float* c1_b2 = (const float*)d_in[10];
  const float* cv_W1 = (const float*)d_in[11];
  const float* cv_b1 = (const float*)d_in[12];
  const float* cv_g  = (const float*)d_in[13];
  const float* cv_be = (const float*)d_in[14];
  const float* cv_rm = (const float*)d_in[15];
  const float* cv_rv = (const float*)d_in[16];
  const float* cv_W2 = (const float*)d_in[17];
  const float* cv_b2 = (const float*)d_in[18];
  const float* ln_W  = (const float*)d_in[19];
  const float* ln_b  = (const float*)d_in[20];
  const float* clsW  = (const float*)d_in[21];
  const float* clsB  = (const float*)d_in[22];

  // workspace layout: two ping-pong h buffers + U/V  (needs ~53.6 MB)
  float* buf0 = (float*)d_ws;
  float* buf1 = buf0 + (size_t)NN * FD;
  float* Uu   = buf1 + (size_t)NN * FD;
  float* Vv   = Uu + (size_t)NN * 6;

  float* outL = (float*)d_out;
  float* outE = outL + (size_t)EE * 6;

  dim3 B(256);
  const int gCopy = (NN * FD / 4) / 256;  // 6250 (exact)
  const int gScat = (EE * 32) / 256;      // 80000 (exact)
  const int gGemm = (NN + 63) / 64;       // 782
  const int gUV   = (NN * 12 + 255) / 256;
  const int gEdge = EE / 4;               // 160000 (exact)

  float* bufs[2] = {buf0, buf1};

  // conv1: agg = x + scatter(x); z = relu(bn(agg@W1+b1)); h = relu(z@W2+b2)
  k_copy<<<gCopy, B, 0, stream>>>(x, buf0);
  k_scatter<<<gScat, B, 0, stream>>>(x, src, dst, buf0);
  k_gemm<<<gGemm, B, 0, stream>>>(buf0, c1_W1, c1_b1, c1_g, c1_be, c1_rm, c1_rv, 1, buf1, NN);
  k_gemm<<<gGemm, B, 0, stream>>>(buf1, c1_W2, c1_b2, nullptr, nullptr, nullptr, nullptr, 0, buf0, NN);
  int cur = 0;

  // 2 more GIN layers
  for (int l = 0; l < 2; ++l) {
    float* hc = bufs[cur];
    float* ho = bufs[1 - cur];
    k_copy<<<gCopy, B, 0, stream>>>(hc, ho);
    k_scatter<<<gScat, B, 0, stream>>>(hc, src, dst, ho);
    k_gemm<<<gGemm, B, 0, stream>>>(ho, cv_W1 + (size_t)l * FD * FD, cv_b1 + l * FD,
                                    cv_g + l * FD, cv_be + l * FD, cv_rm + l * FD,
                                    cv_rv + l * FD, 1, hc, NN);
    k_gemm<<<gGemm, B, 0, stream>>>(hc, cv_W2 + (size_t)l * FD * FD, cv_b2 + l * FD,
                                    nullptr, nullptr, nullptr, nullptr, 0, ho, NN);
    cur = 1 - cur;
  }

  // 2 linear layers
  for (int l = 0; l < 2; ++l) {
    k_gemm<<<gGemm, B, 0, stream>>>(bufs[cur], ln_W + (size_t)l * FD * FD, ln_b + l * FD,
                                    nullptr, nullptr, nullptr, nullptr, 0, bufs[1 - cur], NN);
    cur = 1 - cur;
  }

  // classifier split: U = h@W_top, V = h@W_bot; then edge materialization
  k_uv<<<gUV, B, 0, stream>>>(bufs[cur], clsW, Uu, Vv);
  k_edge<<<gEdge, B, 0, stream>>>(bufs[cur], src, dst, Uu, Vv, clsB, outL, outE);
}